// Round 2
// baseline (561.453 us; speedup 1.0000x reference)
//
#include <hip/hip_runtime.h>

// out[b, e] = x[b, idx[b, e], e]
// x:   [32, 4096, 1024] f32
// idx: [32, 1024] i32
// out: [32, 1024] f32
// 32768 outputs -> 1 thread each. idx load + out store coalesced; x gather
// is inherently scattered (per-lane row). Latency/launch-overhead bound.

#define BS 32
#define SEQ_LEN 4096
#define EMB 1024

__global__ void embracement_gather(const float* __restrict__ x,
                                   const int* __restrict__ idx,
                                   float* __restrict__ out) {
    const int tid = blockIdx.x * blockDim.x + threadIdx.x;  // 0 .. BS*EMB-1
    if (tid >= BS * EMB) return;
    const int b = tid >> 10;        // tid / EMB
    const int e = tid & (EMB - 1);  // tid % EMB
    const int row = idx[tid];       // idx[b, e]
    out[tid] = x[((size_t)b * SEQ_LEN + (size_t)row) * EMB + e];
}

extern "C" void kernel_launch(void* const* d_in, const int* in_sizes, int n_in,
                              void* d_out, int out_size, void* d_ws, size_t ws_size,
                              hipStream_t stream) {
    const float* x   = (const float*)d_in[0];
    const int*   idx = (const int*)d_in[1];
    float*       out = (float*)d_out;

    const int total = BS * EMB;  // 32768
    const int block = 256;
    const int grid  = (total + block - 1) / block;  // 128
    embracement_gather<<<grid, block, 0, stream>>>(x, idx, out);
}